// Round 1
// baseline (1793.844 us; speedup 1.0000x reference)
//
#include <hip/hip_runtime.h>

#define NFEAT 64
#define NCLS  100
#define ACC   (NCLS * NFEAT)   // 6400

// ws layout (floats): [0,6400) = s, [6400,12800) = ss, [12800,12900) = counts(uint)
__global__ void zero_ws_kernel(float* ws) {
    int i = blockIdx.x * blockDim.x + threadIdx.x;
    if (i < 2 * ACC + NCLS) ws[i] = 0.0f;
}

__global__ __launch_bounds__(256, 3)
void accum_kernel(const float* __restrict__ x, const int* __restrict__ t,
                  float* __restrict__ gs, float* __restrict__ gss,
                  unsigned int* __restrict__ gcnt, int nrows) {
    __shared__ float        ls [ACC];
    __shared__ float        lss[ACC];
    __shared__ unsigned int lcnt[NCLS];

    const int tid = threadIdx.x;
    for (int i = tid; i < ACC; i += 256) { ls[i] = 0.0f; lss[i] = 0.0f; }
    if (tid < NCLS) lcnt[tid] = 0u;
    __syncthreads();

    const int lane = tid & 63;          // feature index
    const int wave = tid >> 6;          // 4 waves/block, one row per wave per iter
    const int stride = gridDim.x * 4;

    for (int row = blockIdx.x * 4 + wave; row < nrows; row += stride) {
        // row is wave-uniform -> t[row] scalarizes; force SGPR for addr math
        const int c = __builtin_amdgcn_readfirstlane(t[row]);
        const float v = x[(size_t)row * NFEAT + lane];   // coalesced 256B/wave
        const int base = c * NFEAT + lane;               // 2-way bank alias: free
        atomicAdd(&ls [base], v);
        atomicAdd(&lss[base], v * v);
        if (lane == 0) atomicAdd(&lcnt[c], 1u);
    }
    __syncthreads();

    for (int i = tid; i < ACC; i += 256) {
        atomicAdd(&gs [i], ls [i]);
        atomicAdd(&gss[i], lss[i]);
    }
    if (tid < NCLS) {
        unsigned int n = lcnt[tid];
        if (n) atomicAdd(&gcnt[tid], n);
    }
}

__global__ void finalize_kernel(const float* __restrict__ gs,
                                const float* __restrict__ gss,
                                const unsigned int* __restrict__ gcnt,
                                float* __restrict__ out) {
    __shared__ double red[256];
    double acc = 0.0;
    for (int i = threadIdx.x; i < ACC; i += 256) {
        const int c = i >> 6;
        const double n  = (double)gcnt[c];
        const double s  = (double)gs[i];
        const double ss = (double)gss[i];
        acc += (ss - s * s / n) / (n - 1.0);
    }
    red[threadIdx.x] = acc;
    __syncthreads();
    for (int off = 128; off > 0; off >>= 1) {
        if (threadIdx.x < off) red[threadIdx.x] += red[threadIdx.x + off];
        __syncthreads();
    }
    if (threadIdx.x == 0) out[0] = (float)(red[0] / (double)NCLS);
}

extern "C" void kernel_launch(void* const* d_in, const int* in_sizes, int n_in,
                              void* d_out, int out_size, void* d_ws, size_t ws_size,
                              hipStream_t stream) {
    const float* x = (const float*)d_in[0];
    const int*   t = (const int*)d_in[1];
    const int nrows = in_sizes[1];           // 2,000,000

    float* gs = (float*)d_ws;
    float* gss = gs + ACC;
    unsigned int* gcnt = (unsigned int*)(gss + ACC);

    const int zwords = 2 * ACC + NCLS;       // 12,900
    zero_ws_kernel<<<(zwords + 255) / 256, 256, 0, stream>>>((float*)d_ws);

    // 3 blocks/CU co-resident (LDS-limited); grid-stride covers all rows
    accum_kernel<<<768, 256, 0, stream>>>(x, t, gs, gss, gcnt, nrows);

    finalize_kernel<<<1, 256, 0, stream>>>(gs, gss, gcnt, (float*)d_out);
}